// Round 2
// baseline (269.657 us; speedup 1.0000x reference)
//
#include <hip/hip_runtime.h>

// TAdaConv2d via bf16 MFMA implicit GEMM — fused, barrier-free main loop.
//   out[b,co,t,y,w] = bias[co] + sum_{ci,ky,kx} x[b,ci,t,y+ky-1,w+kx-1]*alpha[b,ci,t]*W[co,ci,ky,kx]
//
// R2 change vs R1 (conv3, 97 us, MfmaUtil 15.5%, all pipes <20% => latency/lockstep-bound):
//   - Weights live in REGISTERS, not LDS. Wave remap: wv -> (q = co-quarter, ph = row pair).
//     Per wave weights = 9 taps x 2 K-halves x bf16x8 = 72 VGPRs, loaded once (18 coalesced
//     1KB loads from re-laid-out wb, L2-hot).
//   - => no wl LDS buffer, no per-tap global prefetch, no per-tap LDS writes, and ZERO
//     __syncthreads after staging (xs is read-only). 9 barriers removed; each wave runs
//     144 MFMA + 144 ds_read_b128 as one independent stream.
//   - ds addressing: wx&7 independent of pixel-tile index n -> 6 address VGPRs (dx x kc),
//     everything else folds into ds_read offset immediates.
//   - LDS = xs only (50.7 KB); __launch_bounds__(512,4) caps VGPR at 128 -> 2 blocks/CU.
// Accumulation order per output element unchanged (tap, kc) -> bit-identical, absmax 0.0156.

#define CIN  64
#define COUT 64
#define TT   16
#define BB   8
#define HH   64
#define WW   64

typedef __attribute__((ext_vector_type(8))) short bf16x8;
typedef __attribute__((ext_vector_type(4))) float f32x4;

__device__ __forceinline__ unsigned short f2bf(float f) {
    // round-to-nearest-even fp32 -> bf16
    union { float f; unsigned u; } v; v.f = f;
    unsigned r = (v.u + 0x7FFF + ((v.u >> 16) & 1)) >> 16;
    return (unsigned short)r;
}

// ---------------- prep_w: weight -> wb[q][tap][kc][kg][co_l][8] bf16 ----------------
// Fragment-direct layout: wave with co-quarter q reads its A-operand for (tap,kc) as one
// coalesced 1KB load: lane (kg*16+co_l) gets co=q*16+co_l, ci=kc*32+kg*8+e.
__global__ __launch_bounds__(256) void prep_w(const float* __restrict__ wgt,
                                              unsigned short* __restrict__ wb) {
    int idx = blockIdx.x * 256 + threadIdx.x;   // over co*ci*tap = 36864
    if (idx < COUT * CIN * 9) {
        int co  = idx / (CIN * 9);
        int r   = idx - co * (CIN * 9);
        int ci  = r / 9;
        int tap = r - ci * 9;
        int q    = co >> 4;
        int co_l = co & 15;
        int kc   = ci >> 5;
        int kg   = (ci >> 3) & 3;
        int e    = ci & 7;
        wb[(((((q * 9 + tap) * 2 + kc) * 4 + kg) * 16) + co_l) * 8 + e] = f2bf(wgt[idx]);
    }
}

// ---------------- conv4: fused stage + register-weight MFMA implicit GEMM ----------------
// block: (bt, ytile): 4 output rows x 64 w, all 64 co. 8 waves = (q co-quarter 0..3) x
// (ph row-pair 0..1). Each wave: 16 co x 2 rows x 64 w.
__global__ __launch_bounds__(512, 4) void conv4(const float* __restrict__ x,
                                                const float* __restrict__ alpha,
                                                const short* __restrict__ wb,
                                                const float* __restrict__ bias,
                                                float* __restrict__ out) {
    __shared__ __align__(16) short xs[6 * 66 * 64];   // 6 rows x (66 px x 64 ci) bf16, 50.7 KB

    // XCD-aware bijective swizzle: 2048 blocks, 8 XCDs.
    const int orig  = blockIdx.x;
    const int blk   = (orig & 7) * 256 + (orig >> 3);
    const int ytile = blk & 15;
    const int bt    = blk >> 4;
    const int t     = bt & 15;
    const int b     = bt >> 4;
    const int y0    = ytile * 4;
    const int tid   = threadIdx.x;
    const int wv    = tid >> 6;          // wave id; ci-group during staging
    const int lane  = tid & 63;
    const int co_l  = lane & 15;
    const int kg    = lane >> 4;
    const int q     = wv & 3;            // co quarter
    const int ph    = wv >> 2;           // row pair (rows y0+2*ph, y0+2*ph+1)

    // ---- weight fragments -> registers (issue first; latency hides under staging) ----
    bf16x8 wreg[9][2];
#pragma unroll
    for (int tap = 0; tap < 9; ++tap)
#pragma unroll
        for (int kc = 0; kc < 2; ++kc)
            wreg[tap][kc] = *(const bf16x8*)(wb + (((q * 9 + tap) * 2 + kc) * 64 + lane) * 8);

    // ---- fused x staging: register transpose, alpha fold, bf16, swizzle ----
    {
        const int cib = wv * 8;
        float a0 = alpha[(b * CIN + cib + 0) * TT + t];
        float a1 = alpha[(b * CIN + cib + 1) * TT + t];
        float a2 = alpha[(b * CIN + cib + 2) * TT + t];
        float a3 = alpha[(b * CIN + cib + 3) * TT + t];
        float a4 = alpha[(b * CIN + cib + 4) * TT + t];
        float a5 = alpha[(b * CIN + cib + 5) * TT + t];
        float a6 = alpha[(b * CIN + cib + 6) * TT + t];
        float a7 = alpha[(b * CIN + cib + 7) * TT + t];
        const float* xb = x + (size_t)((b * CIN + cib) * TT + t) * (HH * WW);
        const int slot = wv ^ (lane & 7);
        const int CI_STRIDE = TT * HH * WW;   // 65536 floats between ci planes
#pragma unroll
        for (int r = 0; r < 6; ++r) {
            const int gy = y0 - 1 + r;
            int4 o = {0, 0, 0, 0};
            if ((unsigned)gy < HH) {
                const float* p = xb + gy * WW + lane;   // 64 lanes -> 256B coalesced
                float v0 = p[0 * CI_STRIDE] * a0;
                float v1 = p[1 * CI_STRIDE] * a1;
                float v2 = p[2 * CI_STRIDE] * a2;
                float v3 = p[3 * CI_STRIDE] * a3;
                float v4 = p[4 * CI_STRIDE] * a4;
                float v5 = p[5 * CI_STRIDE] * a5;
                float v6 = p[6 * CI_STRIDE] * a6;
                float v7 = p[7 * CI_STRIDE] * a7;
                o.x = (int)f2bf(v0) | ((int)f2bf(v1) << 16);
                o.y = (int)f2bf(v2) | ((int)f2bf(v3) << 16);
                o.z = (int)f2bf(v4) | ((int)f2bf(v5) << 16);
                o.w = (int)f2bf(v6) | ((int)f2bf(v7) << 16);
            }
            *(int4*)(xs + r * 4224 + (lane + 1) * 64 + slot * 8) = o;
            // halo columns px=0 and px=65: wave wv zeroes slot wv on each
            if (lane < 2) {
                int4 z = {0, 0, 0, 0};
                *(int4*)(xs + r * 4224 + lane * 65 * 64 + wv * 8) = z;
            }
        }
    }
    __syncthreads();   // the ONLY barrier

    // ---- barrier-free MFMA main loop ----
    f32x4 acc[2][4] = {};
    // per-(dx,kc) ds base indices (shorts); pixel-tile n and xs-row fold into offset imm
    int si[3][2];
#pragma unroll
    for (int dxi = 0; dxi < 3; ++dxi)
#pragma unroll
        for (int kc = 0; kc < 2; ++kc) {
            int wx = co_l + dxi - 1;                       // -1..15
            si[dxi][kc] = (wx + 1) * 64 + (((kc * 4 + kg) ^ (wx & 7)) * 8);
        }

#pragma unroll
    for (int tap = 0; tap < 9; ++tap) {
        const int ky  = tap / 3;
        const int dxi = tap - 3 * ky;                     // 0..2  (dx = dxi-1)
        const int rb  = (ph * 2 + ky) * 4224;             // xs row base (shorts)
#pragma unroll
        for (int kc = 0; kc < 2; ++kc) {
#pragma unroll
            for (int r = 0; r < 2; ++r) {
                const short* rowp = xs + rb + r * 4224 + si[dxi][kc];
#pragma unroll
                for (int n = 0; n < 4; ++n) {
                    bf16x8 bfr = *(const bf16x8*)(rowp + n * 1024);  // offset imm
                    acc[r][n] = __builtin_amdgcn_mfma_f32_16x16x32_bf16(
                        wreg[tap][kc], bfr, acc[r][n], 0, 0, 0);
                }
            }
        }
    }

    // ---- epilogue ----
#pragma unroll
    for (int r = 0; r < 2; ++r) {
        const int y = y0 + ph * 2 + r;
#pragma unroll
        for (int rr = 0; rr < 4; ++rr) {
            const int co = q * 16 + kg * 4 + rr;
            const float bv = bias[co];
            float* op = out + (size_t)(((b * COUT + co) * TT + t) * HH + y) * WW;
#pragma unroll
            for (int n = 0; n < 4; ++n)
                op[n * 16 + co_l] = acc[r][n][rr] + bv;
        }
    }
}

extern "C" void kernel_launch(void* const* d_in, const int* in_sizes, int n_in,
                              void* d_out, int out_size, void* d_ws, size_t ws_size,
                              hipStream_t stream) {
    const float* x      = (const float*)d_in[0];
    const float* alpha  = (const float*)d_in[1];
    const float* weight = (const float*)d_in[2];
    const float* bias   = (const float*)d_in[3];
    float* out          = (float*)d_out;

    // workspace: wb only (73.7 KB)
    unsigned short* wb = (unsigned short*)d_ws;

    hipLaunchKernelGGL(prep_w, dim3(144), dim3(256), 0, stream, weight, wb);
    hipLaunchKernelGGL(conv4, dim3(BB * TT * (HH / 4)), dim3(512), 0, stream,
                       x, alpha, (const short*)wb, bias, out);
}